// Round 1
// 1654.124 us; speedup vs baseline: 2.5828x; 2.5828x over previous
//
#include <hip/hip_runtime.h>

// All bf16 handling manual (no hip_bf16.h). Only kernel_launch() is called.

__device__ int g_isbf;  // 1: tensors are bf16 (ushort), 0: fp32

__device__ __forceinline__ float ldin(const void* p, long long i, int isbf) {
  if (isbf) {
    unsigned v = ((const unsigned short*)p)[i];
    return __uint_as_float(v << 16);
  }
  return ((const float*)p)[i];
}

__device__ __forceinline__ unsigned short f2bf(float f) {
  unsigned u = __float_as_uint(f);
  u += 0x7FFFu + ((u >> 16) & 1u);  // RNE
  return (unsigned short)(u >> 16);
}

// numpy AVX512 reduction tree for n=64 (npyv 4x16-lane accumulators, then
// (a+b)+(c+d) lanewise, then _mm512_reduce_add_ps fold tree). For n=64 each
// accumulator holds pure (once-rounded) products, so this models BOTH
// np.add.reduce (t1/t3) and np.einsum contig-two (t2).
__device__ __forceinline__ float tree64(const float* a) {
  float m[16], u[8], v[4];
#pragma unroll
  for (int l = 0; l < 16; ++l)
    m[l] = __fadd_rn(__fadd_rn(a[l], a[l + 16]), __fadd_rn(a[l + 32], a[l + 48]));
#pragma unroll
  for (int l = 0; l < 8; ++l) u[l] = __fadd_rn(m[l], m[l + 8]);
#pragma unroll
  for (int l = 0; l < 4; ++l) v[l] = __fadd_rn(u[l], u[l + 4]);
  return __fadd_rn(__fadd_rn(v[0], v[2]), __fadd_rn(v[1], v[3]));
}

// ---------------- header layout (float offsets) ----------------
#define O_W1F   0        /* 6144   enc_w1 fp32 [co128][48] */
#define O_W2T   6144     /* 131072 enc_w2 fp32 [ci128][tap16][o64] */
#define O_DWT2  137216   /* 131072 dec_w1 fp32 [q32][ci64][tap16][r4], o=4q+r */
#define O_DW2T2 268288   /* 8192   dec_w2 fp32 [cc32][cil4][tap16][o4 pad] */
#define O_CB    276480   /* 32768  codebook fp32 */
#define O_CN3   309248   /* 512    np-f32 ||code||^2 via tree64 */
#define O_B1    310272
#define O_B2    310400
#define O_DB1   310464
#define O_DB2   310592
#define HDRF    310608   /* header floats = 1,242,432 B */
#define PF      1048576  /* P projection floats: [k512][tap16][oc128] = 4 MB */
#define PERB    1064960  /* per image: z 262144 f32 + idx 4096 int */

__global__ void VQVAE_31525059952911_kernel() {}

// ---------------- dtype detector ----------------
__global__ __launch_bounds__(256) void k_detect(const unsigned* __restrict__ x) {
  __shared__ int red[256];
  int t = threadIdx.x;
  int cnt = 0;
  for (int i = t; i < 2048; i += 256) {
    unsigned h = x[i] & 0xFFFFu;
    unsigned e = (h >> 7) & 0xFFu;
    if (e >= 100u && e <= 140u) cnt++;
  }
  red[t] = cnt;
  __syncthreads();
  for (int s = 128; s > 0; s >>= 1) {
    if (t < s) red[t] += red[t + s];
    __syncthreads();
  }
  if (t == 0) g_isbf = (red[0] > 1024) ? 1 : 0;
}

// ---------------- prep: weights/codebook -> fp32 header (+np-f32 cnorm) ----------------
__global__ __launch_bounds__(256) void k_prep(
    const void* __restrict__ w1, const void* __restrict__ b1,
    const void* __restrict__ w2, const void* __restrict__ b2,
    const void* __restrict__ dw1, const void* __restrict__ db1,
    const void* __restrict__ dw2, const void* __restrict__ db2,
    const void* __restrict__ cb, float* __restrict__ ws) {
  const int isbf = g_isbf;
  int id = blockIdx.x * 256 + threadIdx.x;
  if (id < 6144) { ws[O_W1F + id] = ldin(w1, id, isbf); return; }
  id -= 6144;
  if (id < 131072) {  // enc_w2 [o64][ci128][tap16] -> [ci][tap][o]
    int ci = id >> 10, tap = (id >> 6) & 15, o = id & 63;
    ws[O_W2T + id] = ldin(w2, (o * 128 + ci) * 16 + tap, isbf);
    return;
  }
  id -= 131072;
  if (id < 131072) {  // dec_w1 [o128][ci64][tap16] -> [q][ci][tap][r], o=4q+r
    int r = id & 3, tap = (id >> 2) & 15, ci = (id >> 6) & 63, q = id >> 12;
    ws[O_DWT2 + id] = ldin(dw1, ((q * 4 + r) * 64 + ci) * 16 + tap, isbf);
    return;
  }
  id -= 131072;
  if (id < 8192) {  // dec_w2 [o3][ci128][tap16] -> [cc][cil][tap][o pad4]
    int o = id & 3, tap = (id >> 2) & 15, cil = (id >> 6) & 3, cc = id >> 8;
    ws[O_DW2T2 + id] = (o < 3) ? ldin(dw2, (o * 128 + cc * 4 + cil) * 16 + tap, isbf) : 0.f;
    return;
  }
  id -= 8192;
  if (id < 32768) { ws[O_CB + id] = ldin(cb, id, isbf); return; }
  id -= 32768;
  if (id < 512) {  // ||c||^2 = (cb*cb).sum(-1): f32 squares + tree64
    float q[64];
    for (int d = 0; d < 64; ++d) {
      float v = ldin(cb, id * 64 + d, isbf);
      q[d] = __fmul_rn(v, v);
    }
    ws[O_CN3 + id] = tree64(q);
    return;
  }
  id -= 512;
  if (id < 128) { ws[O_B1 + id] = ldin(b1, id, isbf); return; }
  id -= 128;
  if (id < 64) { ws[O_B2 + id] = ldin(b2, id, isbf); return; }
  id -= 64;
  if (id < 128) { ws[O_DB1 + id] = ldin(db1, id, isbf); return; }
  id -= 4 + 124;
  if (id < 4) { ws[O_DB2 + id] = (id < 3) ? ldin(db2, id, isbf) : 0.f; return; }
}

// ---------------- P projection: P[k][tap][oc] = sum_ci cb[k][ci]*dec_w1[oc][ci][tap] ----------------
// Collapses deconv1's 256-term per-element dot product into 4 table adds.
// 512 blocks (one per code k), 256 threads: oc = t&127, tap-octet = t>>7.
__global__ __launch_bounds__(256) void k_pproj(
    const void* __restrict__ dw1, const void* __restrict__ cb,
    float* __restrict__ P) {
  __shared__ float cbs[64];
  const int isbf = g_isbf;
  const int t = threadIdx.x;
  const int k = blockIdx.x;
  if (t < 64) cbs[t] = ldin(cb, (long long)k * 64 + t, isbf);
  __syncthreads();
  const int oc = t & 127;
  const int th = t >> 7;  // 0..1, taps th*8 .. th*8+7
  float acc[8];
#pragma unroll
  for (int j = 0; j < 8; ++j) acc[j] = 0.f;
  for (int ci = 0; ci < 64; ++ci) {
    const float v = cbs[ci];
    const long long base = ((long long)oc * 64 + ci) * 16 + th * 8;
    float wv[8];
    if (isbf) {
      const uint4 raw = *(const uint4*)((const unsigned short*)dw1 + base);
      wv[0] = __uint_as_float((raw.x & 0xFFFFu) << 16);
      wv[1] = __uint_as_float(raw.x & 0xFFFF0000u);
      wv[2] = __uint_as_float((raw.y & 0xFFFFu) << 16);
      wv[3] = __uint_as_float(raw.y & 0xFFFF0000u);
      wv[4] = __uint_as_float((raw.z & 0xFFFFu) << 16);
      wv[5] = __uint_as_float(raw.z & 0xFFFF0000u);
      wv[6] = __uint_as_float((raw.w & 0xFFFFu) << 16);
      wv[7] = __uint_as_float(raw.w & 0xFFFF0000u);
    } else {
      const float4 a = *(const float4*)((const float*)dw1 + base);
      const float4 b = *(const float4*)((const float*)dw1 + base + 4);
      wv[0] = a.x; wv[1] = a.y; wv[2] = a.z; wv[3] = a.w;
      wv[4] = b.x; wv[5] = b.y; wv[6] = b.z; wv[7] = b.w;
    }
#pragma unroll
    for (int j = 0; j < 8; ++j) acc[j] = fmaf(v, wv[j], acc[j]);
  }
#pragma unroll
  for (int j = 0; j < 8; ++j)
    P[(k << 11) + ((th * 8 + j) << 7) + oc] = acc[j];
}

// ---------------- fused encoder, numpy-f32 replica: conv1(relu) + conv2 -> z (f32) ----------------
// Sequential f32 mul+add in (ci,ky,kx) order (einsum generic-path model).
__global__ __launch_bounds__(256) void k_enc(
    const void* __restrict__ x, const float* __restrict__ w1f,
    const float* __restrict__ w2t, const float* __restrict__ b1,
    const float* __restrict__ b2, float* __restrict__ z, int b0) {
  __shared__ float x_s[3][38][38];
  __shared__ float w2_s[8192];        // [ci8][tap16][o64]
  __shared__ float w1c_s[384];        // [c8][48]
  __shared__ float h1_s[8][18][18];
  __shared__ float b2_s[64];
  __shared__ float b1c_s[8];
  const int isbf = g_isbf;
  const int t = threadIdx.x;
  const int bz = blockIdx.z, y0 = blockIdx.y * 8, x0 = blockIdx.x * 8;
  const long long xbase = (long long)(b0 + bz) * 3 * 65536;
  for (int i = t; i < 4332; i += 256) {  // 3*38*38, x rows 4y0-3 .. 4y0+34
    int ci = i / 1444, rem = i % 1444, lr = rem / 38, lc = rem % 38;
    int iy = 4 * y0 - 3 + lr, ix = 4 * x0 - 3 + lc;
    float v = 0.f;
    if (iy >= 0 && iy < 256 && ix >= 0 && ix < 256)
      v = ldin(x, xbase + (long long)ci * 65536 + iy * 256 + ix, isbf);
    x_s[ci][lr][lc] = v;
  }
  if (t < 64) b2_s[t] = b2[t];
  const int co0 = (t >> 4) * 4;
  const int pg = t & 15, py = pg & 7, px0 = (pg >> 3) * 4;
  float acc[4][4];
#pragma unroll
  for (int c = 0; c < 4; ++c)
#pragma unroll
    for (int u = 0; u < 4; ++u) acc[c][u] = 0.f;
  for (int cc = 0; cc < 16; ++cc) {
    __syncthreads();
    for (int i = t; i < 8192; i += 256) w2_s[i] = w2t[cc * 8192 + i];
    for (int i = t; i < 384; i += 256) w1c_s[i] = w1f[cc * 384 + i];
    if (t < 8) b1c_s[t] = b1[cc * 8 + t];
    __syncthreads();
    // h1 chunk [8][18][18] f32 sequential (ci,ky,kx): rows 2y0-1 .. 2y0+16
    for (int j = t; j < 2592; j += 256) {
      int c = j / 324, rem = j % 324, ly = rem / 18, lx = rem % 18;
      int hy = 2 * y0 - 1 + ly, hx = 2 * x0 - 1 + lx;
      float v = 0.f;
      if (hy >= 0 && hy < 128 && hx >= 0 && hx < 128) {
        const float* wc = &w1c_s[c * 48];
        float a = 0.f;
        for (int ci = 0; ci < 3; ++ci) {
#pragma unroll
          for (int ky = 0; ky < 4; ++ky) {
            const float* xr = &x_s[ci][2 * ly + ky][2 * lx];
            const float* wr = &wc[ci * 16 + ky * 4];
            a = __fadd_rn(a, __fmul_rn(xr[0], wr[0]));
            a = __fadd_rn(a, __fmul_rn(xr[1], wr[1]));
            a = __fadd_rn(a, __fmul_rn(xr[2], wr[2]));
            a = __fadd_rn(a, __fmul_rn(xr[3], wr[3]));
          }
        }
        v = __fadd_rn(a, b1c_s[c]);
        if (v < 0.f) v = 0.f;
      }
      h1_s[c][ly][lx] = v;
    }
    __syncthreads();
    // conv2 accumulate f32 sequential (ci ascending across chunks, ky, kx)
    for (int ci = 0; ci < 8; ++ci) {
#pragma unroll
      for (int ky = 0; ky < 4; ++ky) {
        float xrow[10];
#pragma unroll
        for (int q = 0; q < 10; ++q) xrow[q] = h1_s[ci][2 * py + ky][2 * px0 + q];
#pragma unroll
        for (int kx = 0; kx < 4; ++kx) {
          const float* wp = &w2_s[(ci * 16 + ky * 4 + kx) * 64 + co0];
#pragma unroll
          for (int u = 0; u < 4; ++u) {
            const float xv = xrow[2 * u + kx];
            acc[0][u] = __fadd_rn(acc[0][u], __fmul_rn(xv, wp[0]));
            acc[1][u] = __fadd_rn(acc[1][u], __fmul_rn(xv, wp[1]));
            acc[2][u] = __fadd_rn(acc[2][u], __fmul_rn(xv, wp[2]));
            acc[3][u] = __fadd_rn(acc[3][u], __fmul_rn(xv, wp[3]));
          }
        }
      }
    }
  }
  const long long zb = (long long)bz * 262144;
#pragma unroll
  for (int u = 0; u < 4; ++u) {
    long long pos = (long long)(y0 + py) * 64 + x0 + px0 + u;
#pragma unroll
    for (int c = 0; c < 4; ++c)
      z[zb + (long long)(co0 + c) * 4096 + pos] = __fadd_rn(acc[c][u], b2_s[co0 + c]);
  }
}

// ---------------- VQ argmin: numpy-f32 replica ----------------
// d2 = fl(fl(t1 - fl(2*t2)) + t3); t1/t3/t2 via tree64; strict <, ascending k.
__global__ __launch_bounds__(256) void k_vq(
    const float* __restrict__ z, const float* __restrict__ cb32,
    const float* __restrict__ cn3, int* __restrict__ idx) {
  __shared__ float cb_s[8192];
  __shared__ float cn_s[128];
  const int t = threadIdx.x;
  const long long g = (long long)blockIdx.x * 256 + t;
  float zr[64], q[64];
  for (int d = 0; d < 64; ++d) zr[d] = z[g * 64 + d];
#pragma unroll
  for (int d = 0; d < 64; ++d) q[d] = __fmul_rn(zr[d], zr[d]);
  const float t1 = tree64(q);
  float best = 3.4e38f;
  int bi = 0;
  for (int ch = 0; ch < 4; ++ch) {
    __syncthreads();
    for (int i = t; i < 8192; i += 256) cb_s[i] = cb32[ch * 8192 + i];
    if (t < 128) cn_s[t] = cn3[ch * 128 + t];
    __syncthreads();
    for (int kl = 0; kl < 128; ++kl) {
      const float* cp = &cb_s[kl * 64];
      float p[64];
#pragma unroll
      for (int d = 0; d < 64; ++d) p[d] = __fmul_rn(zr[d], cp[d]);
      const float t2 = tree64(p);
      const float d2 = __fadd_rn(__fsub_rn(t1, __fmul_rn(2.0f, t2)), cn_s[kl]);
      const int k = ch * 128 + kl;
      if (d2 < best) { best = d2; bi = k; }
    }
  }
  idx[g] = bi;
}

// ---------------- fused decoder v2 (fp32): P-gather deconv1(relu) + deconv2 -> out ----------------
// d1[oc][dy][dx] = relu(db1[oc] + sum_{sy,sx} P[idx[..]][tap][oc]) — no ci loop.
__global__ __launch_bounds__(256) void k_dec(
    const int* __restrict__ idxp, const float* __restrict__ P,
    const float* __restrict__ w2t, const float* __restrict__ db1,
    const float* __restrict__ db2, void* __restrict__ outp, int b0) {
  __shared__ int idx_s[6][18];
  __shared__ float d1_s[4][10][35];  // stride 35: break even-bank aliasing
  __shared__ float w2c_s[256];       // [cil4][tap16][o4]
  __shared__ float db1_s[128];
  const int isbf = g_isbf;
  const int t = threadIdx.x;
  const int bz = blockIdx.z, Y0 = blockIdx.y * 16, X0 = blockIdx.x * 64;
  const int yb = (Y0 >> 2) - 1, xb = (X0 >> 2) - 1;
  if (t < 128) db1_s[t] = db1[t];
  for (int j = t; j < 108; j += 256) {
    int r = j / 18, c = j % 18;
    int yin = yb + r, xin = xb + c;
    int k = -1;
    if (yin >= 0 && yin < 64 && xin >= 0 && xin < 64)
      k = idxp[bz * 4096 + yin * 64 + xin];
    idx_s[r][c] = k;
  }
  const int py = t >> 4, px0 = (t & 15) * 4;
  const int ry = py & 1;
  float acc[3][4];
  for (int o = 0; o < 3; ++o)
    for (int e = 0; e < 4; ++e) acc[o][e] = 0.f;
  for (int cc = 0; cc < 32; ++cc) {
    __syncthreads();  // prev dec2 done with d1_s/w2c_s; (first iter: idx_s ready)
    w2c_s[t] = w2t[cc * 256 + t];
    // d1 chunk via P gather: 340 positions, all 4 ocl at once (float4)
    for (int j = t; j < 340; j += 256) {
      int ldy = j / 34, ldx = j % 34;
      int dy = (Y0 >> 1) - 1 + ldy, dx = (X0 >> 1) - 1 + ldx;
      float s0 = 0.f, s1 = 0.f, s2 = 0.f, s3 = 0.f;
      bool inb = (dy >= 0 && dy < 128 && dx >= 0 && dx < 128);
      if (inb) {
        const int kyp = (ldy + 1) & 1, kxp = (ldx + 1) & 1;
        const int lr0 = (ldy + kyp - 1) >> 1, lc0 = (ldx + kxp - 1) >> 1;
#pragma unroll
        for (int sy = 0; sy < 2; ++sy) {
#pragma unroll
          for (int sx = 0; sx < 2; ++sx) {
            const int k = idx_s[lr0 + sy][lc0 + sx];
            if (k >= 0) {
              const int tap = (kyp + 2 * sy) * 4 + (kxp + 2 * sx);
              const float4 pv =
                  *(const float4*)(P + (k << 11) + (tap << 7) + (cc << 2));
              s0 += pv.x; s1 += pv.y; s2 += pv.z; s3 += pv.w;
            }
          }
        }
        s0 += db1_s[cc * 4 + 0]; if (s0 < 0.f) s0 = 0.f;
        s1 += db1_s[cc * 4 + 1]; if (s1 < 0.f) s1 = 0.f;
        s2 += db1_s[cc * 4 + 2]; if (s2 < 0.f) s2 = 0.f;
        s3 += db1_s[cc * 4 + 3]; if (s3 < 0.f) s3 = 0.f;
      }
      d1_s[0][ldy][ldx] = s0;
      d1_s[1][ldy][ldx] = s1;
      d1_s[2][ldy][ldx] = s2;
      d1_s[3][ldy][ldx] = s3;
    }
    __syncthreads();
    // dec2 accumulate: float4 weight loads hoisted per (cl,sy,sx,rx)
    for (int cl = 0; cl < 4; ++cl) {
#pragma unroll
      for (int sy = 0; sy < 2; ++sy) {
        const int ldy = ((py + ry) >> 1) + sy;
#pragma unroll
        for (int sx = 0; sx < 2; ++sx) {
#pragma unroll
          for (int rx = 0; rx < 2; ++rx) {
            const int tap = (ry + 2 * sy) * 4 + rx + 2 * sx;
            const float4 w = *(const float4*)&w2c_s[(cl * 16 + tap) * 4];
#pragma unroll
            for (int ex = 0; ex < 2; ++ex) {
              const int e = 2 * ex + rx;
              const int ldx = ((px0 + e + rx) >> 1) + sx;
              const float dv = d1_s[cl][ldy][ldx];
              acc[0][e] = fmaf(dv, w.x, acc[0][e]);
              acc[1][e] = fmaf(dv, w.y, acc[1][e]);
              acc[2][e] = fmaf(dv, w.z, acc[2][e]);
            }
          }
        }
      }
    }
  }
  const int oy = Y0 + py;
  for (int o = 0; o < 3; ++o) {
    const float bv = db2[o];
    const long long ob = (((long long)(b0 + bz) * 3 + o) * 256 + oy) * 256 + X0 + px0;
    if (isbf) {
      unsigned short* o16 = (unsigned short*)outp;
      for (int e = 0; e < 4; ++e) o16[ob + e] = f2bf(acc[o][e] + bv);
    } else {
      float* o32 = (float*)outp;
      for (int e = 0; e < 4; ++e) o32[ob + e] = acc[o][e] + bv;
    }
  }
}

// ---------------- fused decoder v1 (fp32): zq-LDS deconv1(relu) + deconv2 ----------------
// kept for the tiny-workspace scavenger path only.
__global__ __launch_bounds__(256) void k_deco(
    const int* __restrict__ idxp, const float* __restrict__ cb32,
    const float* __restrict__ dwt2, const float* __restrict__ dw2t2,
    const float* __restrict__ db1, const float* __restrict__ db2,
    void* __restrict__ outp, int b0) {
  __shared__ float zq_s[64][6][18];
  __shared__ float w1c_s[4096];  // [ci64][tap16][oc4]
  __shared__ float w2c_s[256];   // [cil4][tap16][o4]
  __shared__ float d1_s[4][10][34];
  __shared__ float db1_s[128];
  const int isbf = g_isbf;
  const int t = threadIdx.x;
  const int bz = blockIdx.z, Y0 = blockIdx.y * 16, X0 = blockIdx.x * 64;
  const int yb = (Y0 >> 2) - 1, xb = (X0 >> 2) - 1;
  if (t < 128) db1_s[t] = db1[t];
  for (int j = t; j < 6912; j += 256) {
    int ci = j / 108, p = j % 108, r = p / 18, c = p % 18;
    int yin = yb + r, xin = xb + c;
    float v = 0.f;
    if (yin >= 0 && yin < 64 && xin >= 0 && xin < 64) {
      int k = idxp[bz * 4096 + yin * 64 + xin];
      v = cb32[k * 64 + ci];
    }
    zq_s[ci][r][c] = v;
  }
  const int py = t >> 4, px0 = (t & 15) * 4;
  const int ry = py & 1;
  float acc[3][4];
  for (int o = 0; o < 3; ++o)
    for (int e = 0; e < 4; ++e) acc[o][e] = 0.f;
  for (int cc = 0; cc < 32; ++cc) {
    __syncthreads();
    for (int i = t; i < 4096; i += 256) w1c_s[i] = dwt2[cc * 4096 + i];
    if (t < 256) w2c_s[t] = dw2t2[cc * 256 + t];
    __syncthreads();
    for (int j = t; j < 1360; j += 256) {
      int ocl = j / 340, p = j % 340, ldy = p / 34, ldx = p % 34;
      int dy = (Y0 >> 1) - 1 + ldy, dx = (X0 >> 1) - 1 + ldx;
      float val = 0.f;
      if (dy >= 0 && dy < 128 && dx >= 0 && dx < 128) {
        const int kyp = (ldy + 1) & 1, kxp = (ldx + 1) & 1;
        const int lr0 = (ldy + kyp - 1) >> 1, lc0 = (ldx + kxp - 1) >> 1;
        float s = 0.f;
#pragma unroll
        for (int sy = 0; sy < 2; ++sy) {
#pragma unroll
          for (int sx = 0; sx < 2; ++sx) {
            const int tap = (kyp + 2 * sy) * 4 + (kxp + 2 * sx);
            const int lr = lr0 + sy, lc = lc0 + sx;
            const float* wp = &w1c_s[tap * 4 + ocl];
            float ss = 0.f;
            for (int ci = 0; ci < 64; ++ci)
              ss = fmaf(zq_s[ci][lr][lc], wp[ci * 64], ss);
            s += ss;
          }
        }
        val = s + db1_s[cc * 4 + ocl];
        if (val < 0.f) val = 0.f;
      }
      d1_s[ocl][ldy][ldx] = val;
    }
    __syncthreads();
    for (int cl = 0; cl < 4; ++cl) {
#pragma unroll
      for (int e = 0; e < 4; ++e) {
        const int rx = e & 1;
#pragma unroll
        for (int sy = 0; sy < 2; ++sy) {
          const int ky = ry + 2 * sy;
          const int ldy = ((py + ry) >> 1) + sy;
#pragma unroll
          for (int sx = 0; sx < 2; ++sx) {
            const int kx = rx + 2 * sx;
            const int ldx = ((px0 + e + rx) >> 1) + sx;
            const float dv = d1_s[cl][ldy][ldx];
            const float* wp = &w2c_s[(cl * 16 + ky * 4 + kx) * 4];
            acc[0][e] = fmaf(dv, wp[0], acc[0][e]);
            acc[1][e] = fmaf(dv, wp[1], acc[1][e]);
            acc[2][e] = fmaf(dv, wp[2], acc[2][e]);
          }
        }
      }
    }
  }
  const int oy = Y0 + py;
  for (int o = 0; o < 3; ++o) {
    const float bv = db2[o];
    const long long ob = (((long long)(b0 + bz) * 3 + o) * 256 + oy) * 256 + X0 + px0;
    if (isbf) {
      unsigned short* o16 = (unsigned short*)outp;
      for (int e = 0; e < 4; ++e) o16[ob + e] = f2bf(acc[o][e] + bv);
    } else {
      float* o32 = (float*)outp;
      for (int e = 0; e < 4; ++e) o32[ob + e] = acc[o][e] + bv;
    }
  }
}

// ---------------- host-side pipeline ----------------
static void run_chunk_p(const void* x, float* hdr, float* P, float* zb, int* ib,
                        void* out, int C, int b0, hipStream_t stream) {
  dim3 ge(8, 8, C);
  k_enc<<<ge, 256, 0, stream>>>(x, hdr + O_W1F, hdr + O_W2T, hdr + O_B1,
                                hdr + O_B2, zb, b0);
  k_vq<<<16 * C, 256, 0, stream>>>(zb, hdr + O_CB, hdr + O_CN3, ib);
  dim3 gd(4, 16, C);
  k_dec<<<gd, 256, 0, stream>>>(ib, P, hdr + O_DW2T2, hdr + O_DB1,
                                hdr + O_DB2, out, b0);
}

static void run_chunk_o(const void* x, float* hdr, float* zb, int* ib, void* out,
                        int C, int b0, hipStream_t stream) {
  dim3 ge(8, 8, C);
  k_enc<<<ge, 256, 0, stream>>>(x, hdr + O_W1F, hdr + O_W2T, hdr + O_B1,
                                hdr + O_B2, zb, b0);
  k_vq<<<16 * C, 256, 0, stream>>>(zb, hdr + O_CB, hdr + O_CN3, ib);
  dim3 gd(4, 16, C);
  k_deco<<<gd, 256, 0, stream>>>(ib, hdr + O_CB, hdr + O_DWT2, hdr + O_DW2T2,
                                 hdr + O_DB1, hdr + O_DB2, out, b0);
}

extern "C" void kernel_launch(void* const* d_in, const int* in_sizes, int n_in,
                              void* d_out, int out_size, void* d_ws, size_t ws_size,
                              hipStream_t stream) {
  (void)out_size;
  // ---- identify inputs (dict order per harness docs; size-schemes as defense) ----
  const void *x = 0, *w1 = 0, *b1 = 0, *w2 = 0, *b2 = 0;
  const void *dw1 = 0, *db1 = 0, *dw2 = 0, *db2 = 0, *cb = 0;
  static const int dictsz[10] = {6291456, 6144, 128, 131072, 64, 131072, 128, 6144, 3, 32768};
  int isdict = 1;
  if (n_in >= 10) {
    for (int i = 0; i < 10; ++i)
      if (in_sizes[i] != dictsz[i]) isdict = 0;
  } else isdict = 0;
  if (isdict) {
    x = d_in[0]; w1 = d_in[1]; b1 = d_in[2]; w2 = d_in[3]; b2 = d_in[4];
    dw1 = d_in[5]; db1 = d_in[6]; dw2 = d_in[7]; db2 = d_in[8]; cb = d_in[9];
  } else {
    int c6144 = 0, c131072 = 0, c128 = 0;
    for (int i = 0; i < n_in; ++i) {
      switch (in_sizes[i]) {
        case 6291456: x = d_in[i]; break;
        case 32768: cb = d_in[i]; break;
        case 64: b2 = d_in[i]; break;
        case 3: db2 = d_in[i]; break;
        case 6144: if (c6144++ == 0) w1 = d_in[i]; else dw2 = d_in[i]; break;
        case 131072: if (c131072++ == 0) w2 = d_in[i]; else dw1 = d_in[i]; break;
        case 128: if (c128++ == 0) b1 = d_in[i]; else db1 = d_in[i]; break;
        default: break;
      }
    }
    if (!x || !w1 || !b1 || !w2 || !b2 || !dw1 || !db1 || !dw2 || !db2 || !cb) {
      x = d_in[0]; w1 = d_in[1]; b1 = d_in[2]; w2 = d_in[3]; b2 = d_in[4];
      dw1 = d_in[5]; db1 = d_in[6]; dw2 = d_in[7]; db2 = d_in[8]; cb = d_in[9];
    }
  }

  k_detect<<<1, 256, 0, stream>>>((const unsigned*)x);

  const size_t HDRB = (size_t)HDRF * 4;            // 1,242,432 B (old header)
  const size_t HDR2F = (size_t)HDRF + (size_t)PF;  // header + P floats
  const size_t HDR2B = HDR2F * 4;                  // 5,436,736 B

  if (ws_size >= HDR2B + (size_t)PERB) {
    int C = 32;
    while (C > 1 && HDR2B + (size_t)C * PERB > ws_size) C >>= 1;
    float* hdr = (float*)d_ws;
    float* P = hdr + HDRF;
    float* zb = hdr + HDR2F;
    int* ib = (int*)((char*)zb + (size_t)C * 1048576);
    k_prep<<<1212, 256, 0, stream>>>(w1, b1, w2, b2, dw1, db1, dw2, db2, cb, hdr);
    k_pproj<<<512, 256, 0, stream>>>(dw1, cb, P);
    for (int b0 = 0; b0 < 32; b0 += C)
      run_chunk_p(x, hdr, P, zb, ib, d_out, C, b0, stream);
  } else {
    // scavenger: scratch = 2,307,392 B (old layout, old decoder).
    // phase A: scratch = d_out[0, 2.31MB) (out imgs 0..5), process 31..6.
    // phase B: scratch = x bytes [10,275,520, 12,582,912) (x imgs >=26.1,
    //          consumed in phase A), process 5..0.
    {
      float* SA = (float*)d_out;
      float* zb = SA + HDRF;
      int* ib = (int*)((char*)zb + 1048576);
      k_prep<<<1212, 256, 0, stream>>>(w1, b1, w2, b2, dw1, db1, dw2, db2, cb, SA);
      for (int i = 31; i >= 6; --i) run_chunk_o(x, SA, zb, ib, d_out, 1, i, stream);
    }
    {
      float* SB = (float*)((char*)x + 10275520);
      float* zb = SB + HDRF;
      int* ib = (int*)((char*)zb + 1048576);
      k_prep<<<1212, 256, 0, stream>>>(w1, b1, w2, b2, dw1, db1, dw2, db2, cb, SB);
      for (int i = 5; i >= 0; --i) run_chunk_o(x, SB, zb, ib, d_out, 1, i, stream);
    }
  }
}

// Round 2
// 1477.947 us; speedup vs baseline: 2.8907x; 1.1192x over previous
//
#include <hip/hip_runtime.h>

// All bf16 handling manual (no hip_bf16.h). Only kernel_launch() is called.

__device__ int g_isbf;  // 1: tensors are bf16 (ushort), 0: fp32

__device__ __forceinline__ float ldin(const void* p, long long i, int isbf) {
  if (isbf) {
    unsigned v = ((const unsigned short*)p)[i];
    return __uint_as_float(v << 16);
  }
  return ((const float*)p)[i];
}

__device__ __forceinline__ unsigned short f2bf(float f) {
  unsigned u = __float_as_uint(f);
  u += 0x7FFFu + ((u >> 16) & 1u);  // RNE
  return (unsigned short)(u >> 16);
}

// numpy AVX512 reduction tree for n=64 (npyv 4x16-lane accumulators, then
// (a+b)+(c+d) lanewise, then _mm512_reduce_add_ps fold tree). For n=64 each
// accumulator holds pure (once-rounded) products, so this models BOTH
// np.add.reduce (t1/t3) and np.einsum contig-two (t2).
__device__ __forceinline__ float tree64(const float* a) {
  float m[16], u[8], v[4];
#pragma unroll
  for (int l = 0; l < 16; ++l)
    m[l] = __fadd_rn(__fadd_rn(a[l], a[l + 16]), __fadd_rn(a[l + 32], a[l + 48]));
#pragma unroll
  for (int l = 0; l < 8; ++l) u[l] = __fadd_rn(m[l], m[l + 8]);
#pragma unroll
  for (int l = 0; l < 4; ++l) v[l] = __fadd_rn(u[l], u[l + 4]);
  return __fadd_rn(__fadd_rn(v[0], v[2]), __fadd_rn(v[1], v[3]));
}

// ---------------- header layout (float offsets) ----------------
#define O_W1F   0        /* 6144   enc_w1 fp32 [co128][48] */
#define O_W2T   6144     /* 131072 enc_w2 fp32 [ci128][tap16][o64] */
#define O_DWT2  137216   /* 131072 dec_w1 fp32 [q32][ci64][tap16][r4], o=4q+r */
#define O_DW2T2 268288   /* 8192   dec_w2 fp32 [cc32][cil4][tap16][o4 pad] */
#define O_CB    276480   /* 32768  codebook fp32 */
#define O_CN3   309248   /* 512    np-f32 ||code||^2 via tree64 */
#define O_B1    310272
#define O_B2    310400
#define O_DB1   310464
#define O_DB2   310592
#define HDRF    310608   /* header floats = 1,242,432 B */
#define PF      1048576  /* P projection floats: [k512][tap16][oc128] = 4 MB */
#define PERB    1064960  /* per image: z 262144 f32 + idx 4096 int */

__global__ void VQVAE_31525059952911_kernel() {}

// ---------------- dtype detector ----------------
__global__ __launch_bounds__(256) void k_detect(const unsigned* __restrict__ x) {
  __shared__ int red[256];
  int t = threadIdx.x;
  int cnt = 0;
  for (int i = t; i < 2048; i += 256) {
    unsigned h = x[i] & 0xFFFFu;
    unsigned e = (h >> 7) & 0xFFu;
    if (e >= 100u && e <= 140u) cnt++;
  }
  red[t] = cnt;
  __syncthreads();
  for (int s = 128; s > 0; s >>= 1) {
    if (t < s) red[t] += red[t + s];
    __syncthreads();
  }
  if (t == 0) g_isbf = (red[0] > 1024) ? 1 : 0;
}

// ---------------- prep: weights/codebook -> fp32 header (+np-f32 cnorm) ----------------
__global__ __launch_bounds__(256) void k_prep(
    const void* __restrict__ w1, const void* __restrict__ b1,
    const void* __restrict__ w2, const void* __restrict__ b2,
    const void* __restrict__ dw1, const void* __restrict__ db1,
    const void* __restrict__ dw2, const void* __restrict__ db2,
    const void* __restrict__ cb, float* __restrict__ ws) {
  const int isbf = g_isbf;
  int id = blockIdx.x * 256 + threadIdx.x;
  if (id < 6144) { ws[O_W1F + id] = ldin(w1, id, isbf); return; }
  id -= 6144;
  if (id < 131072) {  // enc_w2 [o64][ci128][tap16] -> [ci][tap][o]
    int ci = id >> 10, tap = (id >> 6) & 15, o = id & 63;
    ws[O_W2T + id] = ldin(w2, (o * 128 + ci) * 16 + tap, isbf);
    return;
  }
  id -= 131072;
  if (id < 131072) {  // dec_w1 [o128][ci64][tap16] -> [q][ci][tap][r], o=4q+r
    int r = id & 3, tap = (id >> 2) & 15, ci = (id >> 6) & 63, q = id >> 12;
    ws[O_DWT2 + id] = ldin(dw1, ((q * 4 + r) * 64 + ci) * 16 + tap, isbf);
    return;
  }
  id -= 131072;
  if (id < 8192) {  // dec_w2 [o3][ci128][tap16] -> [cc][cil][tap][o pad4]
    int o = id & 3, tap = (id >> 2) & 15, cil = (id >> 6) & 3, cc = id >> 8;
    ws[O_DW2T2 + id] = (o < 3) ? ldin(dw2, (o * 128 + cc * 4 + cil) * 16 + tap, isbf) : 0.f;
    return;
  }
  id -= 8192;
  if (id < 32768) { ws[O_CB + id] = ldin(cb, id, isbf); return; }
  id -= 32768;
  if (id < 512) {  // ||c||^2 = (cb*cb).sum(-1): f32 squares + tree64
    float q[64];
    for (int d = 0; d < 64; ++d) {
      float v = ldin(cb, id * 64 + d, isbf);
      q[d] = __fmul_rn(v, v);
    }
    ws[O_CN3 + id] = tree64(q);
    return;
  }
  id -= 512;
  if (id < 128) { ws[O_B1 + id] = ldin(b1, id, isbf); return; }
  id -= 128;
  if (id < 64) { ws[O_B2 + id] = ldin(b2, id, isbf); return; }
  id -= 64;
  if (id < 128) { ws[O_DB1 + id] = ldin(db1, id, isbf); return; }
  id -= 4 + 124;
  if (id < 4) { ws[O_DB2 + id] = (id < 3) ? ldin(db2, id, isbf) : 0.f; return; }
}

// ---------------- P projection: P[k][tap][oc] = sum_ci cb[k][ci]*dec_w1[oc][ci][tap] ----------------
__global__ __launch_bounds__(256) void k_pproj(
    const void* __restrict__ dw1, const void* __restrict__ cb,
    float* __restrict__ P) {
  __shared__ float cbs[64];
  const int isbf = g_isbf;
  const int t = threadIdx.x;
  const int k = blockIdx.x;
  if (t < 64) cbs[t] = ldin(cb, (long long)k * 64 + t, isbf);
  __syncthreads();
  const int oc = t & 127;
  const int th = t >> 7;  // 0..1, taps th*8 .. th*8+7
  float acc[8];
#pragma unroll
  for (int j = 0; j < 8; ++j) acc[j] = 0.f;
  for (int ci = 0; ci < 64; ++ci) {
    const float v = cbs[ci];
    const long long base = ((long long)oc * 64 + ci) * 16 + th * 8;
    float wv[8];
    if (isbf) {
      const uint4 raw = *(const uint4*)((const unsigned short*)dw1 + base);
      wv[0] = __uint_as_float((raw.x & 0xFFFFu) << 16);
      wv[1] = __uint_as_float(raw.x & 0xFFFF0000u);
      wv[2] = __uint_as_float((raw.y & 0xFFFFu) << 16);
      wv[3] = __uint_as_float(raw.y & 0xFFFF0000u);
      wv[4] = __uint_as_float((raw.z & 0xFFFFu) << 16);
      wv[5] = __uint_as_float(raw.z & 0xFFFF0000u);
      wv[6] = __uint_as_float((raw.w & 0xFFFFu) << 16);
      wv[7] = __uint_as_float(raw.w & 0xFFFF0000u);
    } else {
      const float4 a = *(const float4*)((const float*)dw1 + base);
      const float4 b = *(const float4*)((const float*)dw1 + base + 4);
      wv[0] = a.x; wv[1] = a.y; wv[2] = a.z; wv[3] = a.w;
      wv[4] = b.x; wv[5] = b.y; wv[6] = b.z; wv[7] = b.w;
    }
#pragma unroll
    for (int j = 0; j < 8; ++j) acc[j] = fmaf(v, wv[j], acc[j]);
  }
#pragma unroll
  for (int j = 0; j < 8; ++j)
    P[(k << 11) + ((th * 8 + j) << 7) + oc] = acc[j];
}

// ---------------- fused encoder, numpy-f32 replica: conv1(relu) + conv2 -> z (f32) ----------------
// Sequential f32 mul+add in (ci,ky,kx) order per output element (einsum
// generic-path model) — bit-exact vs numpy. Restructured for issue rate:
//  * ci-chunk of 4 (32 iters): LDS 40.4 KB -> 4 blocks/CU (16 waves).
//  * x_s row stride 39 (odd, coprime with 16 bank-pairs): conflict-free.
//  * conv1 computes width-3 strips: 3 independent add chains, registered x row.
__global__ __launch_bounds__(256, 4) void k_enc(
    const void* __restrict__ x, const float* __restrict__ w1f,
    const float* __restrict__ w2t, const float* __restrict__ b1,
    const float* __restrict__ b2, float* __restrict__ z, int b0) {
  __shared__ float x_s[3][38][39];   // 17,784 B (stride 39 breaks even-bank lattice)
  __shared__ float w2_s[4096];       // [ci4][tap16][o64] = 16,384 B
  __shared__ float w1c_s[192];       // [c4][48] = 768 B
  __shared__ float h1_s[4][18][18];  // 5,184 B
  __shared__ float b2_s[64];
  __shared__ float b1c_s[4];
  const int isbf = g_isbf;
  const int t = threadIdx.x;
  const int bz = blockIdx.z, y0 = blockIdx.y * 8, x0 = blockIdx.x * 8;
  const long long xbase = (long long)(b0 + bz) * 3 * 65536;
  for (int i = t; i < 4332; i += 256) {  // 3*38*38, x rows 4y0-3 .. 4y0+34
    int ci = i / 1444, rem = i % 1444, lr = rem / 38, lc = rem % 38;
    int iy = 4 * y0 - 3 + lr, ix = 4 * x0 - 3 + lc;
    float v = 0.f;
    if (iy >= 0 && iy < 256 && ix >= 0 && ix < 256)
      v = ldin(x, xbase + (long long)ci * 65536 + iy * 256 + ix, isbf);
    x_s[ci][lr][lc] = v;
  }
  if (t < 64) b2_s[t] = b2[t];
  const int co0 = (t >> 4) * 4;
  const int pg = t & 15, py = pg & 7, px0 = (pg >> 3) * 4;
  float acc[4][4];
#pragma unroll
  for (int c = 0; c < 4; ++c)
#pragma unroll
    for (int u = 0; u < 4; ++u) acc[c][u] = 0.f;
  for (int cc = 0; cc < 32; ++cc) {  // ci chunks of 4
    __syncthreads();
    for (int i = t; i < 4096; i += 256) w2_s[i] = w2t[cc * 4096 + i];
    if (t < 192) w1c_s[t] = w1f[cc * 192 + t];
    if (t < 4) b1c_s[t] = b1[cc * 4 + t];
    __syncthreads();
    // conv1: h1 chunk [4][18][18], width-3 strips (18 = 6*3, exact cover).
    // Per element the FP order is (ci,ky,kx) sequential mul+add — unchanged.
    for (int s = t; s < 432; s += 256) {
      const int c = s / 108, rs = s % 108;
      const int ly = rs / 6, lx0 = (rs % 6) * 3;
      const int hy = 2 * y0 - 1 + ly;
      const int hx0 = 2 * x0 - 1 + lx0;
      float a0 = 0.f, a1 = 0.f, a2 = 0.f;
      const bool rowok = (hy >= 0 && hy < 128);
      if (rowok) {
        const float* wc = &w1c_s[c * 48];
#pragma unroll
        for (int ci = 0; ci < 3; ++ci) {
#pragma unroll
          for (int ky = 0; ky < 4; ++ky) {
            const float* xr = &x_s[ci][2 * ly + ky][2 * lx0];
            const float x0r = xr[0], x1r = xr[1], x2r = xr[2], x3r = xr[3];
            const float x4r = xr[4], x5r = xr[5], x6r = xr[6], x7r = xr[7];
            const float* wr = &wc[ci * 16 + ky * 4];
            const float w0 = wr[0], w1 = wr[1], w2 = wr[2], w3 = wr[3];
            a0 = __fadd_rn(a0, __fmul_rn(x0r, w0));
            a1 = __fadd_rn(a1, __fmul_rn(x2r, w0));
            a2 = __fadd_rn(a2, __fmul_rn(x4r, w0));
            a0 = __fadd_rn(a0, __fmul_rn(x1r, w1));
            a1 = __fadd_rn(a1, __fmul_rn(x3r, w1));
            a2 = __fadd_rn(a2, __fmul_rn(x5r, w1));
            a0 = __fadd_rn(a0, __fmul_rn(x2r, w2));
            a1 = __fadd_rn(a1, __fmul_rn(x4r, w2));
            a2 = __fadd_rn(a2, __fmul_rn(x6r, w2));
            a0 = __fadd_rn(a0, __fmul_rn(x3r, w3));
            a1 = __fadd_rn(a1, __fmul_rn(x5r, w3));
            a2 = __fadd_rn(a2, __fmul_rn(x7r, w3));
          }
        }
      }
      float v0 = 0.f, v1 = 0.f, v2 = 0.f;
      if (rowok) {
        const float bb = b1c_s[c];
        v0 = __fadd_rn(a0, bb); if (v0 < 0.f) v0 = 0.f;
        v1 = __fadd_rn(a1, bb); if (v1 < 0.f) v1 = 0.f;
        v2 = __fadd_rn(a2, bb); if (v2 < 0.f) v2 = 0.f;
        if (hx0 < 0) v0 = 0.f;            // hx0 >= -1, so only v0 can be left-oob
        if (hx0 >= 128) v0 = 0.f;
        if (hx0 + 1 >= 128) v1 = 0.f;
        if (hx0 + 2 >= 128) v2 = 0.f;
      }
      h1_s[c][ly][lx0] = v0;
      h1_s[c][ly][lx0 + 1] = v1;
      h1_s[c][ly][lx0 + 2] = v2;
    }
    __syncthreads();
    // conv2 accumulate f32 sequential (ci ascending across chunks, ky, kx)
    for (int ci = 0; ci < 4; ++ci) {
#pragma unroll
      for (int ky = 0; ky < 4; ++ky) {
        float xrow[10];
#pragma unroll
        for (int q = 0; q < 10; ++q) xrow[q] = h1_s[ci][2 * py + ky][2 * px0 + q];
#pragma unroll
        for (int kx = 0; kx < 4; ++kx) {
          const float4 w = *(const float4*)&w2_s[(ci * 16 + ky * 4 + kx) * 64 + co0];
#pragma unroll
          for (int u = 0; u < 4; ++u) {
            const float xv = xrow[2 * u + kx];
            acc[0][u] = __fadd_rn(acc[0][u], __fmul_rn(xv, w.x));
            acc[1][u] = __fadd_rn(acc[1][u], __fmul_rn(xv, w.y));
            acc[2][u] = __fadd_rn(acc[2][u], __fmul_rn(xv, w.z));
            acc[3][u] = __fadd_rn(acc[3][u], __fmul_rn(xv, w.w));
          }
        }
      }
    }
  }
  const long long zb = (long long)bz * 262144;
#pragma unroll
  for (int u = 0; u < 4; ++u) {
    long long pos = (long long)(y0 + py) * 64 + x0 + px0 + u;
#pragma unroll
    for (int c = 0; c < 4; ++c)
      z[zb + (long long)(co0 + c) * 4096 + pos] = __fadd_rn(acc[c][u], b2_s[co0 + c]);
  }
}

// ---------------- VQ argmin: numpy-f32 replica ----------------
// d2 = fl(fl(t1 - fl(2*t2)) + t3); t1/t3/t2 via tree64; strict <, ascending k.
__global__ __launch_bounds__(256) void k_vq(
    const float* __restrict__ z, const float* __restrict__ cb32,
    const float* __restrict__ cn3, int* __restrict__ idx) {
  __shared__ float cb_s[8192];
  __shared__ float cn_s[128];
  const int t = threadIdx.x;
  const long long g = (long long)blockIdx.x * 256 + t;
  float zr[64], q[64];
  for (int d = 0; d < 64; ++d) zr[d] = z[g * 64 + d];
#pragma unroll
  for (int d = 0; d < 64; ++d) q[d] = __fmul_rn(zr[d], zr[d]);
  const float t1 = tree64(q);
  float best = 3.4e38f;
  int bi = 0;
  for (int ch = 0; ch < 4; ++ch) {
    __syncthreads();
    for (int i = t; i < 8192; i += 256) cb_s[i] = cb32[ch * 8192 + i];
    if (t < 128) cn_s[t] = cn3[ch * 128 + t];
    __syncthreads();
    for (int kl = 0; kl < 128; ++kl) {
      const float* cp = &cb_s[kl * 64];
      float p[64];
#pragma unroll
      for (int d = 0; d < 64; ++d) p[d] = __fmul_rn(zr[d], cp[d]);
      const float t2 = tree64(p);
      const float d2 = __fadd_rn(__fsub_rn(t1, __fmul_rn(2.0f, t2)), cn_s[kl]);
      const int k = ch * 128 + kl;
      if (d2 < best) { best = d2; bi = k; }
    }
  }
  idx[g] = bi;
}

// ---------------- fused decoder v2 (fp32): P-gather deconv1(relu) + deconv2 -> out ----------------
__global__ __launch_bounds__(256) void k_dec(
    const int* __restrict__ idxp, const float* __restrict__ P,
    const float* __restrict__ w2t, const float* __restrict__ db1,
    const float* __restrict__ db2, void* __restrict__ outp, int b0) {
  __shared__ int idx_s[6][18];
  __shared__ float d1_s[4][10][35];  // stride 35: break even-bank aliasing
  __shared__ float w2c_s[256];       // [cil4][tap16][o4]
  __shared__ float db1_s[128];
  const int isbf = g_isbf;
  const int t = threadIdx.x;
  const int bz = blockIdx.z, Y0 = blockIdx.y * 16, X0 = blockIdx.x * 64;
  const int yb = (Y0 >> 2) - 1, xb = (X0 >> 2) - 1;
  if (t < 128) db1_s[t] = db1[t];
  for (int j = t; j < 108; j += 256) {
    int r = j / 18, c = j % 18;
    int yin = yb + r, xin = xb + c;
    int k = -1;
    if (yin >= 0 && yin < 64 && xin >= 0 && xin < 64)
      k = idxp[bz * 4096 + yin * 64 + xin];
    idx_s[r][c] = k;
  }
  const int py = t >> 4, px0 = (t & 15) * 4;
  const int ry = py & 1;
  float acc[3][4];
  for (int o = 0; o < 3; ++o)
    for (int e = 0; e < 4; ++e) acc[o][e] = 0.f;
  for (int cc = 0; cc < 32; ++cc) {
    __syncthreads();  // prev dec2 done with d1_s/w2c_s; (first iter: idx_s ready)
    w2c_s[t] = w2t[cc * 256 + t];
    // d1 chunk via P gather: 340 positions, all 4 ocl at once (float4)
    for (int j = t; j < 340; j += 256) {
      int ldy = j / 34, ldx = j % 34;
      int dy = (Y0 >> 1) - 1 + ldy, dx = (X0 >> 1) - 1 + ldx;
      float s0 = 0.f, s1 = 0.f, s2 = 0.f, s3 = 0.f;
      bool inb = (dy >= 0 && dy < 128 && dx >= 0 && dx < 128);
      if (inb) {
        const int kyp = (ldy + 1) & 1, kxp = (ldx + 1) & 1;
        const int lr0 = (ldy + kyp - 1) >> 1, lc0 = (ldx + kxp - 1) >> 1;
#pragma unroll
        for (int sy = 0; sy < 2; ++sy) {
#pragma unroll
          for (int sx = 0; sx < 2; ++sx) {
            const int k = idx_s[lr0 + sy][lc0 + sx];
            if (k >= 0) {
              const int tap = (kyp + 2 * sy) * 4 + (kxp + 2 * sx);
              const float4 pv =
                  *(const float4*)(P + (k << 11) + (tap << 7) + (cc << 2));
              s0 += pv.x; s1 += pv.y; s2 += pv.z; s3 += pv.w;
            }
          }
        }
        s0 += db1_s[cc * 4 + 0]; if (s0 < 0.f) s0 = 0.f;
        s1 += db1_s[cc * 4 + 1]; if (s1 < 0.f) s1 = 0.f;
        s2 += db1_s[cc * 4 + 2]; if (s2 < 0.f) s2 = 0.f;
        s3 += db1_s[cc * 4 + 3]; if (s3 < 0.f) s3 = 0.f;
      }
      d1_s[0][ldy][ldx] = s0;
      d1_s[1][ldy][ldx] = s1;
      d1_s[2][ldy][ldx] = s2;
      d1_s[3][ldy][ldx] = s3;
    }
    __syncthreads();
    // dec2 accumulate: float4 weight loads hoisted per (cl,sy,sx,rx)
    for (int cl = 0; cl < 4; ++cl) {
#pragma unroll
      for (int sy = 0; sy < 2; ++sy) {
        const int ldy = ((py + ry) >> 1) + sy;
#pragma unroll
        for (int sx = 0; sx < 2; ++sx) {
#pragma unroll
          for (int rx = 0; rx < 2; ++rx) {
            const int tap = (ry + 2 * sy) * 4 + rx + 2 * sx;
            const float4 w = *(const float4*)&w2c_s[(cl * 16 + tap) * 4];
#pragma unroll
            for (int ex = 0; ex < 2; ++ex) {
              const int e = 2 * ex + rx;
              const int ldx = ((px0 + e + rx) >> 1) + sx;
              const float dv = d1_s[cl][ldy][ldx];
              acc[0][e] = fmaf(dv, w.x, acc[0][e]);
              acc[1][e] = fmaf(dv, w.y, acc[1][e]);
              acc[2][e] = fmaf(dv, w.z, acc[2][e]);
            }
          }
        }
      }
    }
  }
  const int oy = Y0 + py;
  for (int o = 0; o < 3; ++o) {
    const float bv = db2[o];
    const long long ob = (((long long)(b0 + bz) * 3 + o) * 256 + oy) * 256 + X0 + px0;
    if (isbf) {
      unsigned short* o16 = (unsigned short*)outp;
      for (int e = 0; e < 4; ++e) o16[ob + e] = f2bf(acc[o][e] + bv);
    } else {
      float* o32 = (float*)outp;
      for (int e = 0; e < 4; ++e) o32[ob + e] = acc[o][e] + bv;
    }
  }
}

// ---------------- fused decoder v1 (fp32): zq-LDS deconv1(relu) + deconv2 ----------------
// kept for the tiny-workspace scavenger path only.
__global__ __launch_bounds__(256) void k_deco(
    const int* __restrict__ idxp, const float* __restrict__ cb32,
    const float* __restrict__ dwt2, const float* __restrict__ dw2t2,
    const float* __restrict__ db1, const float* __restrict__ db2,
    void* __restrict__ outp, int b0) {
  __shared__ float zq_s[64][6][18];
  __shared__ float w1c_s[4096];  // [ci64][tap16][oc4]
  __shared__ float w2c_s[256];   // [cil4][tap16][o4]
  __shared__ float d1_s[4][10][34];
  __shared__ float db1_s[128];
  const int isbf = g_isbf;
  const int t = threadIdx.x;
  const int bz = blockIdx.z, Y0 = blockIdx.y * 16, X0 = blockIdx.x * 64;
  const int yb = (Y0 >> 2) - 1, xb = (X0 >> 2) - 1;
  if (t < 128) db1_s[t] = db1[t];
  for (int j = t; j < 6912; j += 256) {
    int ci = j / 108, p = j % 108, r = p / 18, c = p % 18;
    int yin = yb + r, xin = xb + c;
    float v = 0.f;
    if (yin >= 0 && yin < 64 && xin >= 0 && xin < 64) {
      int k = idxp[bz * 4096 + yin * 64 + xin];
      v = cb32[k * 64 + ci];
    }
    zq_s[ci][r][c] = v;
  }
  const int py = t >> 4, px0 = (t & 15) * 4;
  const int ry = py & 1;
  float acc[3][4];
  for (int o = 0; o < 3; ++o)
    for (int e = 0; e < 4; ++e) acc[o][e] = 0.f;
  for (int cc = 0; cc < 32; ++cc) {
    __syncthreads();
    for (int i = t; i < 4096; i += 256) w1c_s[i] = dwt2[cc * 4096 + i];
    if (t < 256) w2c_s[t] = dw2t2[cc * 256 + t];
    __syncthreads();
    for (int j = t; j < 1360; j += 256) {
      int ocl = j / 340, p = j % 340, ldy = p / 34, ldx = p % 34;
      int dy = (Y0 >> 1) - 1 + ldy, dx = (X0 >> 1) - 1 + ldx;
      float val = 0.f;
      if (dy >= 0 && dy < 128 && dx >= 0 && dx < 128) {
        const int kyp = (ldy + 1) & 1, kxp = (ldx + 1) & 1;
        const int lr0 = (ldy + kyp - 1) >> 1, lc0 = (ldx + kxp - 1) >> 1;
        float s = 0.f;
#pragma unroll
        for (int sy = 0; sy < 2; ++sy) {
#pragma unroll
          for (int sx = 0; sx < 2; ++sx) {
            const int tap = (kyp + 2 * sy) * 4 + (kxp + 2 * sx);
            const int lr = lr0 + sy, lc = lc0 + sx;
            const float* wp = &w1c_s[tap * 4 + ocl];
            float ss = 0.f;
            for (int ci = 0; ci < 64; ++ci)
              ss = fmaf(zq_s[ci][lr][lc], wp[ci * 64], ss);
            s += ss;
          }
        }
        val = s + db1_s[cc * 4 + ocl];
        if (val < 0.f) val = 0.f;
      }
      d1_s[ocl][ldy][ldx] = val;
    }
    __syncthreads();
    for (int cl = 0; cl < 4; ++cl) {
#pragma unroll
      for (int e = 0; e < 4; ++e) {
        const int rx = e & 1;
#pragma unroll
        for (int sy = 0; sy < 2; ++sy) {
          const int ky = ry + 2 * sy;
          const int ldy = ((py + ry) >> 1) + sy;
#pragma unroll
          for (int sx = 0; sx < 2; ++sx) {
            const int kx = rx + 2 * sx;
            const int ldx = ((px0 + e + rx) >> 1) + sx;
            const float dv = d1_s[cl][ldy][ldx];
            const float* wp = &w2c_s[(cl * 16 + ky * 4 + kx) * 4];
            acc[0][e] = fmaf(dv, wp[0], acc[0][e]);
            acc[1][e] = fmaf(dv, wp[1], acc[1][e]);
            acc[2][e] = fmaf(dv, wp[2], acc[2][e]);
          }
        }
      }
    }
  }
  const int oy = Y0 + py;
  for (int o = 0; o < 3; ++o) {
    const float bv = db2[o];
    const long long ob = (((long long)(b0 + bz) * 3 + o) * 256 + oy) * 256 + X0 + px0;
    if (isbf) {
      unsigned short* o16 = (unsigned short*)outp;
      for (int e = 0; e < 4; ++e) o16[ob + e] = f2bf(acc[o][e] + bv);
    } else {
      float* o32 = (float*)outp;
      for (int e = 0; e < 4; ++e) o32[ob + e] = acc[o][e] + bv;
    }
  }
}

// ---------------- host-side pipeline ----------------
static void run_chunk_p(const void* x, float* hdr, float* P, float* zb, int* ib,
                        void* out, int C, int b0, hipStream_t stream) {
  dim3 ge(8, 8, C);
  k_enc<<<ge, 256, 0, stream>>>(x, hdr + O_W1F, hdr + O_W2T, hdr + O_B1,
                                hdr + O_B2, zb, b0);
  k_vq<<<16 * C, 256, 0, stream>>>(zb, hdr + O_CB, hdr + O_CN3, ib);
  dim3 gd(4, 16, C);
  k_dec<<<gd, 256, 0, stream>>>(ib, P, hdr + O_DW2T2, hdr + O_DB1,
                                hdr + O_DB2, out, b0);
}

static void run_chunk_o(const void* x, float* hdr, float* zb, int* ib, void* out,
                        int C, int b0, hipStream_t stream) {
  dim3 ge(8, 8, C);
  k_enc<<<ge, 256, 0, stream>>>(x, hdr + O_W1F, hdr + O_W2T, hdr + O_B1,
                                hdr + O_B2, zb, b0);
  k_vq<<<16 * C, 256, 0, stream>>>(zb, hdr + O_CB, hdr + O_CN3, ib);
  dim3 gd(4, 16, C);
  k_deco<<<gd, 256, 0, stream>>>(ib, hdr + O_CB, hdr + O_DWT2, hdr + O_DW2T2,
                                 hdr + O_DB1, hdr + O_DB2, out, b0);
}

extern "C" void kernel_launch(void* const* d_in, const int* in_sizes, int n_in,
                              void* d_out, int out_size, void* d_ws, size_t ws_size,
                              hipStream_t stream) {
  (void)out_size;
  // ---- identify inputs (dict order per harness docs; size-schemes as defense) ----
  const void *x = 0, *w1 = 0, *b1 = 0, *w2 = 0, *b2 = 0;
  const void *dw1 = 0, *db1 = 0, *dw2 = 0, *db2 = 0, *cb = 0;
  static const int dictsz[10] = {6291456, 6144, 128, 131072, 64, 131072, 128, 6144, 3, 32768};
  int isdict = 1;
  if (n_in >= 10) {
    for (int i = 0; i < 10; ++i)
      if (in_sizes[i] != dictsz[i]) isdict = 0;
  } else isdict = 0;
  if (isdict) {
    x = d_in[0]; w1 = d_in[1]; b1 = d_in[2]; w2 = d_in[3]; b2 = d_in[4];
    dw1 = d_in[5]; db1 = d_in[6]; dw2 = d_in[7]; db2 = d_in[8]; cb = d_in[9];
  } else {
    int c6144 = 0, c131072 = 0, c128 = 0;
    for (int i = 0; i < n_in; ++i) {
      switch (in_sizes[i]) {
        case 6291456: x = d_in[i]; break;
        case 32768: cb = d_in[i]; break;
        case 64: b2 = d_in[i]; break;
        case 3: db2 = d_in[i]; break;
        case 6144: if (c6144++ == 0) w1 = d_in[i]; else dw2 = d_in[i]; break;
        case 131072: if (c131072++ == 0) w2 = d_in[i]; else dw1 = d_in[i]; break;
        case 128: if (c128++ == 0) b1 = d_in[i]; else db1 = d_in[i]; break;
        default: break;
      }
    }
    if (!x || !w1 || !b1 || !w2 || !b2 || !dw1 || !db1 || !dw2 || !db2 || !cb) {
      x = d_in[0]; w1 = d_in[1]; b1 = d_in[2]; w2 = d_in[3]; b2 = d_in[4];
      dw1 = d_in[5]; db1 = d_in[6]; dw2 = d_in[7]; db2 = d_in[8]; cb = d_in[9];
    }
  }

  k_detect<<<1, 256, 0, stream>>>((const unsigned*)x);

  const size_t HDRB = (size_t)HDRF * 4;            // 1,242,432 B (old header)
  const size_t HDR2F = (size_t)HDRF + (size_t)PF;  // header + P floats
  const size_t HDR2B = HDR2F * 4;                  // 5,436,736 B

  if (ws_size >= HDR2B + (size_t)PERB) {
    int C = 32;
    while (C > 1 && HDR2B + (size_t)C * PERB > ws_size) C >>= 1;
    float* hdr = (float*)d_ws;
    float* P = hdr + HDRF;
    float* zb = hdr + HDR2F;
    int* ib = (int*)((char*)zb + (size_t)C * 1048576);
    k_prep<<<1212, 256, 0, stream>>>(w1, b1, w2, b2, dw1, db1, dw2, db2, cb, hdr);
    k_pproj<<<512, 256, 0, stream>>>(dw1, cb, P);
    for (int b0 = 0; b0 < 32; b0 += C)
      run_chunk_p(x, hdr, P, zb, ib, d_out, C, b0, stream);
  } else {
    // scavenger: scratch = 2,307,392 B (old layout, old decoder).
    {
      float* SA = (float*)d_out;
      float* zb = SA + HDRF;
      int* ib = (int*)((char*)zb + 1048576);
      k_prep<<<1212, 256, 0, stream>>>(w1, b1, w2, b2, dw1, db1, dw2, db2, cb, SA);
      for (int i = 31; i >= 6; --i) run_chunk_o(x, SA, zb, ib, d_out, 1, i, stream);
    }
    {
      float* SB = (float*)((char*)x + 10275520);
      float* zb = SB + HDRF;
      int* ib = (int*)((char*)zb + 1048576);
      k_prep<<<1212, 256, 0, stream>>>(w1, b1, w2, b2, dw1, db1, dw2, db2, cb, SB);
      for (int i = 5; i >= 0; --i) run_chunk_o(x, SB, zb, ib, d_out, 1, i, stream);
    }
  }
}